// Round 18
// baseline (236.071 us; speedup 1.0000x reference)
//
#include <hip/hip_runtime.h>
#include <hip/hip_bf16.h>

typedef unsigned short u16;
typedef unsigned int u32;
typedef __attribute__((ext_vector_type(8))) short bfrag;   // 8 bf16 (4 VGPRs)
typedef __attribute__((ext_vector_type(4))) float f32x4;

#define DEVINL __device__ __forceinline__

DEVINL u16 f2bf(float f) {
  u32 u = __float_as_uint(f);
  u32 r = (u + 0x7fffu + ((u >> 16) & 1u)) >> 16;   // RNE
  return (u16)r;
}
DEVINL float bf2f(u16 u) { return __uint_as_float(((u32)u) << 16); }
// HW packed f32->bf16 (RNE), 1 inst for 2 elements
DEVINL u32 cvtpk(float lo, float hi) {
  u32 r;
  asm("v_cvt_pk_bf16_f32 %0, %1, %2" : "=v"(r) : "v"(lo), "v"(hi));
  return r;
}
DEVINL u16 f2bf_hw(float v) { return (u16)cvtpk(v, v); }
DEVINL float fmax3(float a, float b, float c) { return fmaxf(fmaxf(a, b), c); }  // fuses to v_max3_f32

DEVINL void gload_lds16(const void* g, void* l) {
  __builtin_amdgcn_global_load_lds(
      (const __attribute__((address_space(1))) void*)g,
      (__attribute__((address_space(3))) void*)l, 16, 0, 0);
}

DEVINL void storeC(u16* C, size_t idx, float v) { C[idx] = f2bf_hw(v); }
DEVINL void storeC(float* C, size_t idx, float v) { C[idx] = v; }

#define SBAR0 __builtin_amdgcn_sched_barrier(0)

// XCD-affine decode for 512-block (64 M x 8 N) GEMM grids.
DEVINL void gemm_decode(int gid, int& m0, int& n0) {
  const int m = ((gid >> 6) << 3) | (gid & 7);
  const int n = (gid >> 3) & 7;
  m0 = m * 128;
  n0 = n * 128;
}

// ---------------- prep kernels ----------------

// fused cast of the 4 weight matrices (1024 blocks each)
__global__ void cast_w4(const float* __restrict__ w0, const float* __restrict__ w1,
                        const float* __restrict__ w2, const float* __restrict__ w3,
                        u16* __restrict__ o0, u16* __restrict__ o1,
                        u16* __restrict__ o2, u16* __restrict__ o3) {
  const int which = blockIdx.x >> 10;
  const int i = (blockIdx.x & 1023) * 256 + threadIdx.x;
  const float* in = which == 0 ? w0 : which == 1 ? w1 : which == 2 ? w2 : w3;
  u16* out = which == 0 ? o0 : which == 1 ? o1 : which == 2 ? o2 : o3;
  const float4 f = ((const float4*)in)[i];
  uint2 r;
  r.x = cvtpk(f.x, f.y);
  r.y = cvtpk(f.z, f.w);
  ((uint2*)out)[i] = r;
}

__global__ void pack_mask(const int* __restrict__ mask, u32* __restrict__ bits) {
  const size_t wi = (size_t)blockIdx.x * 256 + threadIdx.x;
  const int* src = mask + wi * 32;
  u32 v = 0;
#pragma unroll
  for (int i = 0; i < 8; ++i) {
    const int4 m4 = ((const int4*)src)[i];
    if (m4.x) v |= 1u << (i * 4 + 0);
    if (m4.y) v |= 1u << (i * 4 + 1);
    if (m4.z) v |= 1u << (i * 4 + 2);
    if (m4.w) v |= 1u << (i * 4 + 3);
  }
  bits[wi] = v;
}

// transpose-cast: out[j][k] = bf16(in[k][j]), 1024x1024, grid(16,16), 256 thr
__global__ void transpose_cast(const float* __restrict__ in, u16* __restrict__ out) {
  __shared__ u16 tile[64][65];
  const int t = threadIdx.x;
  const int bx = blockIdx.x, by = blockIdx.y;
#pragma unroll
  for (int p = 0; p < 4; ++p) {
    const int r = (t >> 4) + p * 16;
    const int c = (t & 15) * 4;
    const float4 f = *(const float4*)&in[(size_t)(by * 64 + r) * 1024 + bx * 64 + c];
    tile[c + 0][r] = f2bf(f.x);
    tile[c + 1][r] = f2bf(f.y);
    tile[c + 2][r] = f2bf(f.z);
    tile[c + 3][r] = f2bf(f.w);
  }
  __syncthreads();
#pragma unroll
  for (int p = 0; p < 4; ++p) {
    const int r = (t >> 4) + p * 16;
    const int c = (t & 15) * 4;
    uint2 v;
    v.x = (u32)tile[r][c] | ((u32)tile[r][c + 1] << 16);
    v.y = (u32)tile[r][c + 2] | ((u32)tile[r][c + 3] << 16);
    *(uint2*)&out[(size_t)(bx * 64 + r) * 1024 + by * 64 + c] = v;
  }
}

// bo2 = Wo @ bo + bo ; one wave per output row
__global__ void bias2(const float* __restrict__ wo, const float* __restrict__ bo,
                      float* __restrict__ bo2) {
  const int w = threadIdx.x >> 6, lane = threadIdx.x & 63;
  const int row = blockIdx.x * 4 + w;
  const float* src = wo + (size_t)row * 1024;
  float s = 0.f;
#pragma unroll
  for (int i = 0; i < 4; ++i) {
    const float4 f = *(const float4*)&src[lane * 4 + i * 256];
    const float4 g = *(const float4*)&bo[lane * 4 + i * 256];
    s += f.x * g.x + f.y * g.y + f.z * g.z + f.w * g.w;
  }
#pragma unroll
  for (int d = 1; d < 64; d <<= 1) s += __shfl_xor(s, d);
  if (lane == 0) bo2[row] = s + bo[row];
}

// small GEMM, 64x64 tile (for W2 = Wo@Wo): C = A @ W^T, no bias
__global__ __launch_bounds__(256) void gemm_bt_64(
    const u16* __restrict__ A, const u16* __restrict__ W,
    u16* __restrict__ C, int N, int K) {
  __shared__ u16 sA[64 * 64];
  __shared__ u16 sB[64 * 64];
  const int t = threadIdx.x;
  const int w = t >> 6, lane = t & 63;
  const int lr = lane & 15, lk = (lane >> 4) * 8;
  const int m0 = blockIdx.x * 64, n0 = blockIdx.y * 64;
  f32x4 acc[4] = {};
  for (int k0 = 0; k0 < K; k0 += 64) {
#pragma unroll
    for (int i = 0; i < 2; ++i) {
      const int idx = i * 256 + t;
      const int row = idx >> 3;
      const int col = (idx & 7) * 8;
      gload_lds16(A + (size_t)(m0 + row) * K + k0 + col, &sA[idx * 8]);
      gload_lds16(W + (size_t)(n0 + row) * K + k0 + col, &sB[idx * 8]);
    }
    __syncthreads();
#pragma unroll
    for (int ks = 0; ks < 2; ++ks) {
      const bfrag av = *(const bfrag*)&sA[(w * 16 + lr) * 64 + ks * 32 + lk];
#pragma unroll
      for (int n = 0; n < 4; ++n) {
        const bfrag bv = *(const bfrag*)&sB[(n * 16 + lr) * 64 + ks * 32 + lk];
        acc[n] = __builtin_amdgcn_mfma_f32_16x16x32_bf16(av, bv, acc[n], 0, 0, 0);
      }
    }
    __syncthreads();
  }
  const int orow = (lane >> 4) * 4;
#pragma unroll
  for (int n = 0; n < 4; ++n)
#pragma unroll
    for (int j = 0; j < 4; ++j)
      C[(size_t)(m0 + w * 16 + orow + j) * N + n0 + n * 16 + lr] = f2bf_hw(acc[n][j]);
}

// ---------------- fused QKV projection GEMM ----------------
// grid 1536 = 3 x 512 (which = gid>>9). Single-buffered 32KB LDS (m97 recipe):
// with 1536 blocks resident ~5 blocks/CU, cross-block overlap hides the
// barrier drains. A fp32 -> regs (issued pre-barrier) -> cvt_pk -> swizzled
// ds_write; W bf16 via gload_lds (pre-swizzled source).
// Epilogue: Q (*qs), K, or V^T.   [R13-proven text: 227us total. Pipelining
// attempts R14/R15/R17 all lost through regs/ordering/occupancy — keep simple.]

__global__ __launch_bounds__(256) void gemm_qkv(
    const float* __restrict__ Aq, const float* __restrict__ Ak, const float* __restrict__ Av,
    const u16* __restrict__ Wq, const u16* __restrict__ Wk, const u16* __restrict__ Wv,
    const float* __restrict__ Bq, const float* __restrict__ Bk, const float* __restrict__ Bv,
    u16* __restrict__ Qb, u16* __restrict__ Kb, u16* __restrict__ Vt, float qs) {
  __shared__ __align__(16) u16 sA[128 * 64];
  __shared__ __align__(16) u16 sB[128 * 64];
  const int gid = blockIdx.x;
  const int which = gid >> 9;
  int m0, n0;
  gemm_decode(gid & 511, m0, n0);
  const float* A = which == 0 ? Aq : which == 1 ? Ak : Av;
  const u16* W = which == 0 ? Wq : which == 1 ? Wk : Wv;
  const float* bias = which == 0 ? Bq : which == 1 ? Bk : Bv;
  const int t = threadIdx.x;
  const int w = t >> 6, lane = t & 63;
  const int lr = lane & 15, lg = lane >> 4;
  const int wr = (w >> 1) * 64, wc = (w & 1) * 64;
  f32x4 acc[4][4] = {};

  for (int kt = 0; kt < 16; ++kt) {
    const int k0 = kt * 64;
    f32x4 fa[4][2];
#pragma unroll
    for (int i = 0; i < 4; ++i) {       // A loads in flight before the barrier
      const int idx = i * 256 + t;
      const int row = idx >> 3;
      const int cg = idx & 7;
      const float* src = A + (size_t)(m0 + row) * 1024 + k0 + cg * 8;
      fa[i][0] = *(const f32x4*)src;
      fa[i][1] = *(const f32x4*)(src + 4);
    }
    if (kt) __syncthreads();            // previous compute done with LDS
#pragma unroll
    for (int i = 0; i < 4; ++i) {
      const int idx = i * 256 + t;
      const int row = idx >> 3;
      const int cg = idx & 7;
      uint4 pk;
      pk.x = cvtpk(fa[i][0][0], fa[i][0][1]);
      pk.y = cvtpk(fa[i][0][2], fa[i][0][3]);
      pk.z = cvtpk(fa[i][1][0], fa[i][1][1]);
      pk.w = cvtpk(fa[i][1][2], fa[i][1][3]);
      *(uint4*)((char*)sA + row * 128 + ((cg ^ (row & 7)) * 16)) = pk;
      gload_lds16(W + (size_t)(n0 + row) * 1024 + k0 + ((cg ^ (row & 7)) * 8),
                  (char*)sB + idx * 16);
    }
    __syncthreads();                    // drains vmcnt+lgkm; tile ready
#pragma unroll
    for (int ks = 0; ks < 2; ++ks) {
      bfrag av[4], bv[4];
#pragma unroll
      for (int m = 0; m < 4; ++m) {
        const int row = wr + m * 16 + lr;
        av[m] = *(const bfrag*)((const char*)sA + row * 128 + ((ks * 64 + lg * 16) ^ ((row & 7) << 4)));
      }
#pragma unroll
      for (int n = 0; n < 4; ++n) {
        const int row = wc + n * 16 + lr;
        bv[n] = *(const bfrag*)((const char*)sB + row * 128 + ((ks * 64 + lg * 16) ^ ((row & 7) << 4)));
      }
#pragma unroll
      for (int m = 0; m < 4; ++m)
#pragma unroll
        for (int n = 0; n < 4; ++n)
          acc[m][n] = __builtin_amdgcn_mfma_f32_16x16x32_bf16(av[m], bv[n], acc[m][n], 0, 0, 0);
    }
  }

  float bz[4];
#pragma unroll
  for (int n = 0; n < 4; ++n) bz[n] = bias[n0 + wc + n * 16 + lr];
  const int orow = lg * 4;
  if (which == 2) {                     // V: transposed store Vt[((b*16+h)*64+d)*1024+s]
#pragma unroll
    for (int m = 0; m < 4; ++m) {
#pragma unroll
      for (int n = 0; n < 4; ++n) {
        const int r0 = m0 + wr + m * 16 + orow;
        const int c = n0 + wc + n * 16 + lr;
        const int bb = r0 >> 10, s = r0 & 1023;
        const int h = c >> 6, d = c & 63;
        uint2 v;
        v.x = cvtpk(acc[m][n][0] + bz[n], acc[m][n][1] + bz[n]);
        v.y = cvtpk(acc[m][n][2] + bz[n], acc[m][n][3] + bz[n]);
        *(uint2*)&Vt[(((size_t)bb * 16 + h) * 64 + d) * 1024 + s] = v;
      }
    }
  } else {
    u16* C = which == 0 ? Qb : Kb;
    const float osc = which == 0 ? qs : 1.0f;
#pragma unroll
    for (int m = 0; m < 4; ++m) {
#pragma unroll
      for (int n = 0; n < 4; ++n) {
        const int r = m0 + wr + m * 16 + orow;
        const int c = n0 + wc + n * 16 + lr;
#pragma unroll
        for (int j = 0; j < 4; ++j)
          C[(size_t)(r + j) * 1024 + c] = f2bf_hw((acc[m][n][j] + bz[n]) * osc);
      }
    }
  }
}

// ---------------- final GEMM: C[M,N] = A[M,K] @ W[N,K]^T + bias (fp32 out) ----------------
// 128x128 tile, BK=64, 4 waves. T2 XOR-swizzled LDS + double-buffered,
// 1-ahead prefetch, ONE raw barrier per k-iter. (R13 proven)

template <typename OutT>
__global__ __launch_bounds__(256) void gemm_bt_a16(
    const u16* __restrict__ A, const u16* __restrict__ W,
    const float* __restrict__ bias, OutT* __restrict__ C,
    int M, int N, int K) {
  __shared__ __align__(16) u16 sA[2][128 * 64];
  __shared__ __align__(16) u16 sB[2][128 * 64];
  const int t = threadIdx.x;
  const int w = t >> 6, lane = t & 63;
  const int lr = lane & 15, lg = lane >> 4;
  int m0, n0;
  gemm_decode(blockIdx.x, m0, n0);
  const int wr = (w >> 1) * 64, wc = (w & 1) * 64;
  f32x4 acc[4][4] = {};
  const int nk = K >> 6;

#pragma unroll
  for (int i = 0; i < 4; ++i) {
    const int idx = i * 256 + t;
    const int row = idx >> 3;
    const int col = ((idx & 7) ^ (row & 7)) * 8;   // pre-swizzled source
    gload_lds16(A + (size_t)(m0 + row) * K + col, (char*)sA[0] + idx * 16);
    gload_lds16(W + (size_t)(n0 + row) * K + col, (char*)sB[0] + idx * 16);
  }
  SBAR0; asm volatile("s_waitcnt vmcnt(0)" ::: "memory"); SBAR0;
  __builtin_amdgcn_s_barrier(); SBAR0;

#pragma unroll 2
  for (int kt = 0; kt < nk; ++kt) {
    const int cur = kt & 1;
    if (kt < nk - 1) {
      const int k0 = (kt + 1) * 64;
#pragma unroll
      for (int i = 0; i < 4; ++i) {
        const int idx = i * 256 + t;
        const int row = idx >> 3;
        const int col = ((idx & 7) ^ (row & 7)) * 8;
        gload_lds16(A + (size_t)(m0 + row) * K + k0 + col, (char*)sA[cur ^ 1] + idx * 16);
        gload_lds16(W + (size_t)(n0 + row) * K + k0 + col, (char*)sB[cur ^ 1] + idx * 16);
      }
    }
    const char* pA = (const char*)sA[cur];
    const char* pB = (const char*)sB[cur];
#pragma unroll
    for (int ks = 0; ks < 2; ++ks) {
      bfrag av[4], bv[4];
#pragma unroll
      for (int m = 0; m < 4; ++m) {
        const int row = wr + m * 16 + lr;
        av[m] = *(const bfrag*)(pA + row * 128 + ((ks * 64 + lg * 16) ^ ((row & 7) << 4)));
      }
#pragma unroll
      for (int n = 0; n < 4; ++n) {
        const int row = wc + n * 16 + lr;
        bv[n] = *(const bfrag*)(pB + row * 128 + ((ks * 64 + lg * 16) ^ ((row & 7) << 4)));
      }
#pragma unroll
      for (int m = 0; m < 4; ++m)
#pragma unroll
        for (int n = 0; n < 4; ++n)
          acc[m][n] = __builtin_amdgcn_mfma_f32_16x16x32_bf16(av[m], bv[n], acc[m][n], 0, 0, 0);
    }
    if (kt < nk - 1) {
      SBAR0; asm volatile("s_waitcnt vmcnt(0)" ::: "memory"); SBAR0;
      __builtin_amdgcn_s_barrier(); SBAR0;
    }
  }

  float bz[4];
#pragma unroll
  for (int n = 0; n < 4; ++n) bz[n] = bias[n0 + wc + n * 16 + lr];
  const int orow = lg * 4;
#pragma unroll
  for (int m = 0; m < 4; ++m) {
#pragma unroll
    for (int n = 0; n < 4; ++n) {
      const int r = m0 + wr + m * 16 + orow;
      const int c = n0 + wc + n * 16 + lr;
#pragma unroll
      for (int j = 0; j < 4; ++j)
        storeC(C, (size_t)(r + j) * N + c, acc[m][n][j] + bz[n]);
    }
  }
}

// ---------------- attention ----------------
// R12/R13 proven kernel (98us): R9 structure + h-affinity + fp32-pos direct
// (log2e via FMA), __launch_bounds__(512,4). Unchanged.
// LDS (48KB): [0:8K) K1 | [8K:16K) V1 | [16K:24K) K0 | [24K:32K) V0 | [32K:48K) sP

__global__ __launch_bounds__(512, 4) void attn_fwd(
    const u16* __restrict__ Qm, const u16* __restrict__ Km,
    const u16* __restrict__ Vt, const float* __restrict__ pos,
    const u32* __restrict__ mbits, u16* __restrict__ Om) {
  const int gid = blockIdx.x;
  const int h = (gid & 7) + 8 * (gid >> 9);
  const int inner = (gid >> 3) & 63;
  const int bb = inner & 7;
  const int qt = inner >> 3;
  const int t = threadIdx.x;
  const int w = t >> 6, lane = t & 63;
  const int lr = lane & 15, lg = lane >> 4;
  const float log2e = 1.4426950408889634f;

  __shared__ __align__(16) char smem[49152];

  const int q0 = qt * 128;
  const size_t baseQ = ((size_t)bb * 1024) * 1024 + (size_t)h * 64;
  const size_t baseV = ((size_t)(bb * 16 + h) * 64) * 1024;
  const int qg = q0 + w * 16 + lr;
  const float* posrow = pos + ((size_t)h * 1024 + qg) * 1024;
  const u32* mrow = mbits + ((size_t)bb * 1024 + qg) * 32;

  // stage Q (128x64, swizzled via source permutation) + kt=0 K/V into buf0
#pragma unroll
  for (int i = 0; i < 2; ++i) {
    const int idx = i * 512 + t;
    const int r = idx >> 3;
    const int w8 = idx & 7;
    gload_lds16(Qm + baseQ + (size_t)(q0 + r) * 1024 + (w8 ^ (r & 7)) * 8, smem + idx * 16);
  }
  {
    const int r = t >> 3;
    const int w8 = t & 7;
    gload_lds16(Km + baseQ + (size_t)r * 1024 + (w8 ^ (r & 7)) * 8, smem + 16384 + t * 16);
    gload_lds16(Vt + baseV + (size_t)r * 1024 + (w8 ^ (r & 7)) * 8, smem + 24576 + t * 16);
  }

  // uniform-mask scan (1 bit per k; all-ones rows skip masking entirely)
  u32 ok = 0xffffffffu;
#pragma unroll
  for (int i = 0; i < 8; ++i) {
    const uint4 m4 = *(const uint4*)&mrow[i * 4];
    ok &= m4.x & m4.y & m4.z & m4.w;
  }
  const bool allone = __all(ok == 0xffffffffu);

  float4 pz[4];
#pragma unroll
  for (int n = 0; n < 4; ++n) pz[n] = *(const float4*)&posrow[n * 16 + lg * 4];

  __syncthreads();  // Q + buf0 landed

  // hoist Q fragments (B-operand)
  bfrag qv[2];
#pragma unroll
  for (int ks = 0; ks < 2; ++ks) {
    const int byt = (w * 16 + lr) * 128 + ((ks * 64 + lg * 16) ^ ((lr & 7) << 4));
    qv[ks] = *(const bfrag*)(smem + byt);
  }
  __syncthreads();  // everyone hoisted; sQ region may be overwritten

  f32x4 o[4] = {};
  float m_q = -3.0e38f, l_q = 0.f;

  for (int kt = 0; kt < 16; ++kt) {
    const int cur = kt & 1;
    const char* sK = smem + (cur ? 0 : 16384);
    const char* sV = smem + (cur ? 8192 : 24576);

    float4 pzn[4];
    if (kt < 15) {
      const int kn = (kt + 1) * 64;
      char* dK = smem + (cur ? 16384 : 0);
      char* dV = smem + (cur ? 24576 : 8192);
      const int r = t >> 3;
      const int w8 = t & 7;
      gload_lds16(Km + baseQ + (size_t)(kn + r) * 1024 + (w8 ^ (r & 7)) * 8, dK + t * 16);
      gload_lds16(Vt + baseV + (size_t)r * 1024 + kn + (w8 ^ (r & 7)) * 8, dV + t * 16);
#pragma unroll
      for (int n = 0; n < 4; ++n) pzn[n] = *(const float4*)&posrow[kn + n * 16 + lg * 4];
    }

    // S^T[k][q] = mfma(K, Q); lane: k-local = n*16 + lg*4 + j, q = qg
    f32x4 s[4] = {};
    __builtin_amdgcn_s_setprio(1);
#pragma unroll
    for (int ks = 0; ks < 2; ++ks) {
#pragma unroll
      for (int n = 0; n < 4; ++n) {
        const int byt = (n * 16 + lr) * 128 + ((ks * 64 + lg * 16) ^ ((lr & 7) << 4));
        const bfrag kf = *(const bfrag*)(sK + byt);
        s[n] = __builtin_amdgcn_mfma_f32_16x16x32_bf16(kf, qv[ks], s[n], 0, 0, 0);
      }
    }
    __builtin_amdgcn_s_setprio(0);

    // pos add: pv = s + pos*log2e (fp32 pos, FMA; exp2 domain)
    float pv[16];
#pragma unroll
    for (int n = 0; n < 4; ++n) {
      pv[n * 4 + 0] = fmaf(pz[n].x, log2e, s[n][0]);
      pv[n * 4 + 1] = fmaf(pz[n].y, log2e, s[n][1]);
      pv[n * 4 + 2] = fmaf(pz[n].z, log2e, s[n][2]);
      pv[n * 4 + 3] = fmaf(pz[n].w, log2e, s[n][3]);
    }

    if (!allone) {   // wave-uniform; never taken for all-ones masks
      const u32 a0 = mrow[kt * 2], a1 = mrow[kt * 2 + 1];
#pragma unroll
      for (int n = 0; n < 4; ++n)
#pragma unroll
        for (int j = 0; j < 4; ++j) {
          const int kl = n * 16 + lg * 4 + j;
          const u32 mw = (kl & 32) ? a1 : a0;
          if (!((mw >> (kl & 31)) & 1u)) pv[n * 4 + j] = -1.0e9f;
        }
    }

    // max over 16 (v_max3 tree) + cross-group
    float tmax = fmax3(pv[0], pv[1], pv[2]);
    tmax = fmax3(tmax, pv[3], pv[4]);
    tmax = fmax3(tmax, pv[5], pv[6]);
    tmax = fmax3(tmax, pv[7], pv[8]);
    tmax = fmax3(tmax, pv[9], pv[10]);
    tmax = fmax3(tmax, pv[11], pv[12]);
    tmax = fmax3(tmax, pv[13], pv[14]);
    tmax = fmaxf(tmax, pv[15]);
    tmax = fmaxf(tmax, __shfl_xor(tmax, 16));
    tmax = fmaxf(tmax, __shfl_xor(tmax, 32));

    if (!__all(tmax <= m_q + 8.0f)) {       // defer-max (T13)
      const float mn = fmaxf(m_q, tmax);
      const float sc = __builtin_amdgcn_exp2f(m_q - mn);
      l_q *= sc;
#pragma unroll
      for (int j = 0; j < 4; ++j) {
        const float scj = __shfl(sc, lg * 4 + j);
#pragma unroll
        for (int n = 0; n < 4; ++n) o[n][j] *= scj;
      }
      m_q = mn;
    }
    float rs = 0.f;
#pragma unroll
    for (int i2 = 0; i2 < 16; ++i2) {
      pv[i2] = __builtin_amdgcn_exp2f(pv[i2] - m_q);
      rs += pv[i2];
    }
    rs += __shfl_xor(rs, 16);
    rs += __shfl_xor(rs, 32);
    l_q += rs;

    // P -> per-wave swizzled LDS, read back as A-fragment
    char* pbuf = smem + 32768 + w * 2048;
#pragma unroll
    for (int n = 0; n < 4; ++n) {
      uint2 pk;
      pk.x = cvtpk(pv[n * 4 + 0], pv[n * 4 + 1]);
      pk.y = cvtpk(pv[n * 4 + 2], pv[n * 4 + 3]);
      const int byt = lr * 128 + ((n * 32 + lg * 8) ^ ((lr & 7) << 4));
      *(uint2*)(pbuf + byt) = pk;
    }
    __builtin_amdgcn_s_setprio(1);
#pragma unroll
    for (int ks = 0; ks < 2; ++ks) {
      const int pbyt = lr * 128 + ((ks * 64 + lg * 16) ^ ((lr & 7) << 4));
      const bfrag pf = *(const bfrag*)(pbuf + pbyt);
#pragma unroll
      for (int n = 0; n < 4; ++n) {
        const int vb = (n * 16 + lr) * 128 + ((ks * 64 + lg * 16) ^ ((lr & 7) << 4));
        const bfrag vf = *(const bfrag*)(sV + vb);
        o[n] = __builtin_amdgcn_mfma_f32_16x16x32_bf16(pf, vf, o[n], 0, 0, 0);
      }
    }
    __builtin_amdgcn_s_setprio(0);

    __syncthreads();   // drains prefetch vmcnt; next buffers ready

    if (kt < 15) {
#pragma unroll
      for (int n = 0; n < 4; ++n) pz[n] = pzn[n];
    }
  }

  // normalize + write x_attn[b, q, h*64 + d]
#pragma unroll
  for (int j = 0; j < 4; ++j) {
    const float lj = __shfl(l_q, lg * 4 + j);
    const float inv = 1.f / lj;
    const int qr = q0 + w * 16 + lg * 4 + j;
#pragma unroll
    for (int n = 0; n < 4; ++n)
      Om[baseQ + (size_t)qr * 1024 + n * 16 + lr] = f2bf_hw(o[n][j] * inv);
  }
}

// ---------------- launch ----------------

extern "C" void kernel_launch(void* const* d_in, const int* in_sizes, int n_in,
                              void* d_out, int out_size, void* d_ws, size_t ws_size,
                              hipStream_t stream) {
  const float* query = (const float*)d_in[0];
  const float* key_  = (const float*)d_in[1];
  const float* value = (const float*)d_in[2];
  const int*   mask  = (const int*)d_in[3];
  const float* pos   = (const float*)d_in[4];
  const float* wq = (const float*)d_in[5];
  const float* bq = (const float*)d_in[6];
  const float* wk = (const float*)d_in[7];
  const float* bk = (const float*)d_in[8];
  const float* wv = (const float*)d_in[9];
  const float* bv = (const float*)d_in[10];
  const float* wo = (const float*)d_in[11];
  const float* bo = (const float*)d_in[12];

  char* ws = (char*)d_ws;
  const size_t MB = 1024 * 1024;
  u16* wqb  = (u16*)(ws + 0 * MB);
  u16* wkb  = (u16*)(ws + 2 * MB);
  u16* wvb  = (u16*)(ws + 4 * MB);
  u16* wob  = (u16*)(ws + 6 * MB);
  u16* Qb   = (u16*)(ws + 40 * MB);    // 16MB
  u16* Kb   = (u16*)(ws + 56 * MB);
  u16* Vtb  = (u16*)(ws + 72 * MB);    // 16MB  [B,H,64,S] bf16 (V transposed)
  u16* Xa   = (u16*)(ws + 88 * MB);
  u32* mb   = (u32*)(ws + 104 * MB);   // 1MB bitmask
  u16* wotb = (u16*)(ws + 105 * MB);   // 2MB  Wo^T bf16
  u16* W2b  = (u16*)(ws + 107 * MB);   // 2MB  (Wo@Wo) bf16
  float* bo2 = (float*)(ws + 109 * MB);            // 4KB

  const float log2e = 1.4426950408889634f;
  const float qs = 0.0883883476483184f * log2e;   // (1/sqrt(2*dk)) * log2e

  cast_w4<<<4096, 256, 0, stream>>>(wq, wk, wv, wo, wqb, wkb, wvb, wob);
  pack_mask<<<1024, 256, 0, stream>>>(mask, mb);
  transpose_cast<<<dim3(16, 16), 256, 0, stream>>>(wo, wotb);
  bias2<<<256, 256, 0, stream>>>(wo, bo, bo2);

  // W2 = Wo @ Wo  (A = Wo bf16, W-input = Wo^T in [N][K] layout)
  gemm_bt_64<<<dim3(16, 16), 256, 0, stream>>>(wob, wotb, W2b, 1024, 1024);

  // fused Q/K/V projections: 3 x 512 blocks in ONE launch -> ~5 blocks/CU
  gemm_qkv<<<1536, 256, 0, stream>>>(query, key_, value, wqb, wkb, wvb,
                                     bq, bk, bv, Qb, Kb, Vtb, qs);

  attn_fwd<<<1024, 512, 0, stream>>>(Qb, Kb, Vtb, pos, mb, Xa);

  // out = Xa @ W2^T + bo2   (folds the doubled output linear)
  gemm_bt_a16<float><<<512, 256, 0, stream>>>(Xa, W2b, bo2, (float*)d_out, 8192, 1024, 1024);
}

// Round 19
// 225.117 us; speedup vs baseline: 1.0487x; 1.0487x over previous
//
#include <hip/hip_runtime.h>
#include <hip/hip_bf16.h>

typedef unsigned short u16;
typedef unsigned int u32;
typedef __attribute__((ext_vector_type(8))) short bfrag;   // 8 bf16 (4 VGPRs)
typedef __attribute__((ext_vector_type(4))) float f32x4;

#define DEVINL __device__ __forceinline__

DEVINL u16 f2bf(float f) {
  u32 u = __float_as_uint(f);
  u32 r = (u + 0x7fffu + ((u >> 16) & 1u)) >> 16;   // RNE
  return (u16)r;
}
DEVINL float bf2f(u16 u) { return __uint_as_float(((u32)u) << 16); }
// HW packed f32->bf16 (RNE), 1 inst for 2 elements
DEVINL u32 cvtpk(float lo, float hi) {
  u32 r;
  asm("v_cvt_pk_bf16_f32 %0, %1, %2" : "=v"(r) : "v"(lo), "v"(hi));
  return r;
}
DEVINL u16 f2bf_hw(float v) { return (u16)cvtpk(v, v); }
DEVINL float fmax3(float a, float b, float c) { return fmaxf(fmaxf(a, b), c); }  // fuses to v_max3_f32

DEVINL void gload_lds16(const void* g, void* l) {
  __builtin_amdgcn_global_load_lds(
      (const __attribute__((address_space(1))) void*)g,
      (__attribute__((address_space(3))) void*)l, 16, 0, 0);
}

DEVINL void storeC(u16* C, size_t idx, float v) { C[idx] = f2bf_hw(v); }
DEVINL void storeC(float* C, size_t idx, float v) { C[idx] = v; }

#define SBAR0 __builtin_amdgcn_sched_barrier(0)

// XCD-affine decode for 512-block (64 M x 8 N) GEMM grids.
DEVINL void gemm_decode(int gid, int& m0, int& n0) {
  const int m = ((gid >> 6) << 3) | (gid & 7);
  const int n = (gid >> 3) & 7;
  m0 = m * 128;
  n0 = n * 128;
}

// ---------------- fused prep kernel ----------------
// 5632 blocks, block-uniform branches:
//   [0,4096)    cast_w4: 4 weight matrices fp32->bf16
//   [4096,5120) pack_mask: [B,S,S] int -> bitmask
//   [5120,5376) transpose_cast: Wo^T bf16 (grid 16x16 flattened)
//   [5376,5632) bias2: bo2 = Wo @ bo + bo  (4 rows/block)

__global__ void prep_all(const float* __restrict__ wq, const float* __restrict__ wk,
                         const float* __restrict__ wv, const float* __restrict__ wo,
                         u16* __restrict__ o0, u16* __restrict__ o1,
                         u16* __restrict__ o2, u16* __restrict__ o3,
                         const int* __restrict__ mask, u32* __restrict__ bits,
                         u16* __restrict__ wot, const float* __restrict__ bo,
                         float* __restrict__ bo2) {
  __shared__ u16 tile[64][65];
  const int b = blockIdx.x;
  const int t = threadIdx.x;

  if (b < 4096) {                        // ---- cast_w4 ----
    const int which = b >> 10;
    const int i = (b & 1023) * 256 + t;
    const float* in = which == 0 ? wq : which == 1 ? wk : which == 2 ? wv : wo;
    u16* out = which == 0 ? o0 : which == 1 ? o1 : which == 2 ? o2 : o3;
    const float4 f = ((const float4*)in)[i];
    uint2 r;
    r.x = cvtpk(f.x, f.y);
    r.y = cvtpk(f.z, f.w);
    ((uint2*)out)[i] = r;
  } else if (b < 5120) {                 // ---- pack_mask ----
    const size_t wi = (size_t)(b - 4096) * 256 + t;
    const int* src = mask + wi * 32;
    u32 v = 0;
#pragma unroll
    for (int i = 0; i < 8; ++i) {
      const int4 m4 = ((const int4*)src)[i];
      if (m4.x) v |= 1u << (i * 4 + 0);
      if (m4.y) v |= 1u << (i * 4 + 1);
      if (m4.z) v |= 1u << (i * 4 + 2);
      if (m4.w) v |= 1u << (i * 4 + 3);
    }
    bits[wi] = v;
  } else if (b < 5376) {                 // ---- transpose_cast (Wo^T) ----
    const int bb = b - 5120;
    const int bx = bb & 15, by = bb >> 4;
#pragma unroll
    for (int p = 0; p < 4; ++p) {
      const int r = (t >> 4) + p * 16;
      const int c = (t & 15) * 4;
      const float4 f = *(const float4*)&wo[(size_t)(by * 64 + r) * 1024 + bx * 64 + c];
      tile[c + 0][r] = f2bf(f.x);
      tile[c + 1][r] = f2bf(f.y);
      tile[c + 2][r] = f2bf(f.z);
      tile[c + 3][r] = f2bf(f.w);
    }
    __syncthreads();
#pragma unroll
    for (int p = 0; p < 4; ++p) {
      const int r = (t >> 4) + p * 16;
      const int c = (t & 15) * 4;
      uint2 v;
      v.x = (u32)tile[r][c] | ((u32)tile[r][c + 1] << 16);
      v.y = (u32)tile[r][c + 2] | ((u32)tile[r][c + 3] << 16);
      *(uint2*)&wot[(size_t)(bx * 64 + r) * 1024 + by * 64 + c] = v;
    }
  } else {                               // ---- bias2 ----
    const int w = t >> 6, lane = t & 63;
    const int row = (b - 5376) * 4 + w;
    const float* src = wo + (size_t)row * 1024;
    float s = 0.f;
#pragma unroll
    for (int i = 0; i < 4; ++i) {
      const float4 f = *(const float4*)&src[lane * 4 + i * 256];
      const float4 g = *(const float4*)&bo[lane * 4 + i * 256];
      s += f.x * g.x + f.y * g.y + f.z * g.z + f.w * g.w;
    }
#pragma unroll
    for (int d = 1; d < 64; d <<= 1) s += __shfl_xor(s, d);
    if (lane == 0) bo2[row] = s + bo[row];
  }
}

// small GEMM, 64x64 tile (for W2 = Wo@Wo): C = A @ W^T, no bias
__global__ __launch_bounds__(256) void gemm_bt_64(
    const u16* __restrict__ A, const u16* __restrict__ W,
    u16* __restrict__ C, int N, int K) {
  __shared__ u16 sA[64 * 64];
  __shared__ u16 sB[64 * 64];
  const int t = threadIdx.x;
  const int w = t >> 6, lane = t & 63;
  const int lr = lane & 15, lk = (lane >> 4) * 8;
  const int m0 = blockIdx.x * 64, n0 = blockIdx.y * 64;
  f32x4 acc[4] = {};
  for (int k0 = 0; k0 < K; k0 += 64) {
#pragma unroll
    for (int i = 0; i < 2; ++i) {
      const int idx = i * 256 + t;
      const int row = idx >> 3;
      const int col = (idx & 7) * 8;
      gload_lds16(A + (size_t)(m0 + row) * K + k0 + col, &sA[idx * 8]);
      gload_lds16(W + (size_t)(n0 + row) * K + k0 + col, &sB[idx * 8]);
    }
    __syncthreads();
#pragma unroll
    for (int ks = 0; ks < 2; ++ks) {
      const bfrag av = *(const bfrag*)&sA[(w * 16 + lr) * 64 + ks * 32 + lk];
#pragma unroll
      for (int n = 0; n < 4; ++n) {
        const bfrag bv = *(const bfrag*)&sB[(n * 16 + lr) * 64 + ks * 32 + lk];
        acc[n] = __builtin_amdgcn_mfma_f32_16x16x32_bf16(av, bv, acc[n], 0, 0, 0);
      }
    }
    __syncthreads();
  }
  const int orow = (lane >> 4) * 4;
#pragma unroll
  for (int n = 0; n < 4; ++n)
#pragma unroll
    for (int j = 0; j < 4; ++j)
      C[(size_t)(m0 + w * 16 + orow + j) * N + n0 + n * 16 + lr] = f2bf_hw(acc[n][j]);
}

// ---------------- fused QKV projection GEMM ----------------
// grid 1536 = 3 x 512 (which = gid>>9). Single-buffered 32KB LDS (m97 recipe):
// with 1536 blocks resident ~5 blocks/CU, cross-block overlap hides the
// barrier drains. A fp32 -> regs (issued pre-barrier) -> cvt_pk -> swizzled
// ds_write; W bf16 via gload_lds (pre-swizzled source).
// Epilogue: Q (*qs), K, or V^T.   [R13-proven text]

__global__ __launch_bounds__(256) void gemm_qkv(
    const float* __restrict__ Aq, const float* __restrict__ Ak, const float* __restrict__ Av,
    const u16* __restrict__ Wq, const u16* __restrict__ Wk, const u16* __restrict__ Wv,
    const float* __restrict__ Bq, const float* __restrict__ Bk, const float* __restrict__ Bv,
    u16* __restrict__ Qb, u16* __restrict__ Kb, u16* __restrict__ Vt, float qs) {
  __shared__ __align__(16) u16 sA[128 * 64];
  __shared__ __align__(16) u16 sB[128 * 64];
  const int gid = blockIdx.x;
  const int which = gid >> 9;
  int m0, n0;
  gemm_decode(gid & 511, m0, n0);
  const float* A = which == 0 ? Aq : which == 1 ? Ak : Av;
  const u16* W = which == 0 ? Wq : which == 1 ? Wk : Wv;
  const float* bias = which == 0 ? Bq : which == 1 ? Bk : Bv;
  const int t = threadIdx.x;
  const int w = t >> 6, lane = t & 63;
  const int lr = lane & 15, lg = lane >> 4;
  const int wr = (w >> 1) * 64, wc = (w & 1) * 64;
  f32x4 acc[4][4] = {};

  for (int kt = 0; kt < 16; ++kt) {
    const int k0 = kt * 64;
    f32x4 fa[4][2];
#pragma unroll
    for (int i = 0; i < 4; ++i) {       // A loads in flight before the barrier
      const int idx = i * 256 + t;
      const int row = idx >> 3;
      const int cg = idx & 7;
      const float* src = A + (size_t)(m0 + row) * 1024 + k0 + cg * 8;
      fa[i][0] = *(const f32x4*)src;
      fa[i][1] = *(const f32x4*)(src + 4);
    }
    if (kt) __syncthreads();            // previous compute done with LDS
#pragma unroll
    for (int i = 0; i < 4; ++i) {
      const int idx = i * 256 + t;
      const int row = idx >> 3;
      const int cg = idx & 7;
      uint4 pk;
      pk.x = cvtpk(fa[i][0][0], fa[i][0][1]);
      pk.y = cvtpk(fa[i][0][2], fa[i][0][3]);
      pk.z = cvtpk(fa[i][1][0], fa[i][1][1]);
      pk.w = cvtpk(fa[i][1][2], fa[i][1][3]);
      *(uint4*)((char*)sA + row * 128 + ((cg ^ (row & 7)) * 16)) = pk;
      gload_lds16(W + (size_t)(n0 + row) * 1024 + k0 + ((cg ^ (row & 7)) * 8),
                  (char*)sB + idx * 16);
    }
    __syncthreads();                    // drains vmcnt+lgkm; tile ready
#pragma unroll
    for (int ks = 0; ks < 2; ++ks) {
      bfrag av[4], bv[4];
#pragma unroll
      for (int m = 0; m < 4; ++m) {
        const int row = wr + m * 16 + lr;
        av[m] = *(const bfrag*)((const char*)sA + row * 128 + ((ks * 64 + lg * 16) ^ ((row & 7) << 4)));
      }
#pragma unroll
      for (int n = 0; n < 4; ++n) {
        const int row = wc + n * 16 + lr;
        bv[n] = *(const bfrag*)((const char*)sB + row * 128 + ((ks * 64 + lg * 16) ^ ((row & 7) << 4)));
      }
#pragma unroll
      for (int m = 0; m < 4; ++m)
#pragma unroll
        for (int n = 0; n < 4; ++n)
          acc[m][n] = __builtin_amdgcn_mfma_f32_16x16x32_bf16(av[m], bv[n], acc[m][n], 0, 0, 0);
    }
  }

  float bz[4];
#pragma unroll
  for (int n = 0; n < 4; ++n) bz[n] = bias[n0 + wc + n * 16 + lr];
  const int orow = lg * 4;
  if (which == 2) {                     // V: transposed store Vt[((b*16+h)*64+d)*1024+s]
#pragma unroll
    for (int m = 0; m < 4; ++m) {
#pragma unroll
      for (int n = 0; n < 4; ++n) {
        const int r0 = m0 + wr + m * 16 + orow;
        const int c = n0 + wc + n * 16 + lr;
        const int bb = r0 >> 10, s = r0 & 1023;
        const int h = c >> 6, d = c & 63;
        uint2 v;
        v.x = cvtpk(acc[m][n][0] + bz[n], acc[m][n][1] + bz[n]);
        v.y = cvtpk(acc[m][n][2] + bz[n], acc[m][n][3] + bz[n]);
        *(uint2*)&Vt[(((size_t)bb * 16 + h) * 64 + d) * 1024 + s] = v;
      }
    }
  } else {
    u16* C = which == 0 ? Qb : Kb;
    const float osc = which == 0 ? qs : 1.0f;
#pragma unroll
    for (int m = 0; m < 4; ++m) {
#pragma unroll
      for (int n = 0; n < 4; ++n) {
        const int r = m0 + wr + m * 16 + orow;
        const int c = n0 + wc + n * 16 + lr;
#pragma unroll
        for (int j = 0; j < 4; ++j)
          C[(size_t)(r + j) * 1024 + c] = f2bf_hw((acc[m][n][j] + bz[n]) * osc);
      }
    }
  }
}

// ---------------- final GEMM: C[M,N] = A[M,K] @ W[N,K]^T + bias (fp32 out) ----------------
// 128x128 tile, BK=64, 4 waves. T2 XOR-swizzled LDS + double-buffered,
// 1-ahead prefetch, ONE raw barrier per k-iter. (R13 proven)

template <typename OutT>
__global__ __launch_bounds__(256) void gemm_bt_a16(
    const u16* __restrict__ A, const u16* __restrict__ W,
    const float* __restrict__ bias, OutT* __restrict__ C,
    int M, int N, int K) {
  __shared__ __align__(16) u16 sA[2][128 * 64];
  __shared__ __align__(16) u16 sB[2][128 * 64];
  const int t = threadIdx.x;
  const int w = t >> 6, lane = t & 63;
  const int lr = lane & 15, lg = lane >> 4;
  int m0, n0;
  gemm_decode(blockIdx.x, m0, n0);
  const int wr = (w >> 1) * 64, wc = (w & 1) * 64;
  f32x4 acc[4][4] = {};
  const int nk = K >> 6;

#pragma unroll
  for (int i = 0; i < 4; ++i) {
    const int idx = i * 256 + t;
    const int row = idx >> 3;
    const int col = ((idx & 7) ^ (row & 7)) * 8;   // pre-swizzled source
    gload_lds16(A + (size_t)(m0 + row) * K + col, (char*)sA[0] + idx * 16);
    gload_lds16(W + (size_t)(n0 + row) * K + col, (char*)sB[0] + idx * 16);
  }
  SBAR0; asm volatile("s_waitcnt vmcnt(0)" ::: "memory"); SBAR0;
  __builtin_amdgcn_s_barrier(); SBAR0;

#pragma unroll 2
  for (int kt = 0; kt < nk; ++kt) {
    const int cur = kt & 1;
    if (kt < nk - 1) {
      const int k0 = (kt + 1) * 64;
#pragma unroll
      for (int i = 0; i < 4; ++i) {
        const int idx = i * 256 + t;
        const int row = idx >> 3;
        const int col = ((idx & 7) ^ (row & 7)) * 8;
        gload_lds16(A + (size_t)(m0 + row) * K + k0 + col, (char*)sA[cur ^ 1] + idx * 16);
        gload_lds16(W + (size_t)(n0 + row) * K + k0 + col, (char*)sB[cur ^ 1] + idx * 16);
      }
    }
    const char* pA = (const char*)sA[cur];
    const char* pB = (const char*)sB[cur];
#pragma unroll
    for (int ks = 0; ks < 2; ++ks) {
      bfrag av[4], bv[4];
#pragma unroll
      for (int m = 0; m < 4; ++m) {
        const int row = wr + m * 16 + lr;
        av[m] = *(const bfrag*)(pA + row * 128 + ((ks * 64 + lg * 16) ^ ((row & 7) << 4)));
      }
#pragma unroll
      for (int n = 0; n < 4; ++n) {
        const int row = wc + n * 16 + lr;
        bv[n] = *(const bfrag*)(pB + row * 128 + ((ks * 64 + lg * 16) ^ ((row & 7) << 4)));
      }
#pragma unroll
      for (int m = 0; m < 4; ++m)
#pragma unroll
        for (int n = 0; n < 4; ++n)
          acc[m][n] = __builtin_amdgcn_mfma_f32_16x16x32_bf16(av[m], bv[n], acc[m][n], 0, 0, 0);
    }
    if (kt < nk - 1) {
      SBAR0; asm volatile("s_waitcnt vmcnt(0)" ::: "memory"); SBAR0;
      __builtin_amdgcn_s_barrier(); SBAR0;
    }
  }

  float bz[4];
#pragma unroll
  for (int n = 0; n < 4; ++n) bz[n] = bias[n0 + wc + n * 16 + lr];
  const int orow = lg * 4;
#pragma unroll
  for (int m = 0; m < 4; ++m) {
#pragma unroll
    for (int n = 0; n < 4; ++n) {
      const int r = m0 + wr + m * 16 + orow;
      const int c = n0 + wc + n * 16 + lr;
#pragma unroll
      for (int j = 0; j < 4; ++j)
        storeC(C, (size_t)(r + j) * N + c, acc[m][n][j] + bz[n]);
    }
  }
}

// ---------------- attention ----------------
// R12/R13 proven kernel (98us): R9 structure + h-affinity + fp32-pos direct
// (log2e via FMA), __launch_bounds__(512,4). Unchanged.
// LDS (48KB): [0:8K) K1 | [8K:16K) V1 | [16K:24K) K0 | [24K:32K) V0 | [32K:48K) sP

__global__ __launch_bounds__(512, 4) void attn_fwd(
    const u16* __restrict__ Qm, const u16* __restrict__ Km,
    const u16* __restrict__ Vt, const float* __restrict__ pos,
    const u32* __restrict__ mbits, u16* __restrict__ Om) {
  const int gid = blockIdx.x;
  const int h = (gid & 7) + 8 * (gid >> 9);
  const int inner = (gid >> 3) & 63;
  const int bb = inner & 7;
  const int qt = inner >> 3;
  const int t = threadIdx.x;
  const int w = t >> 6, lane = t & 63;
  const int lr = lane & 15, lg = lane >> 4;
  const float log2e = 1.4426950408889634f;

  __shared__ __align__(16) char smem[49152];

  const int q0 = qt * 128;
  const size_t baseQ = ((size_t)bb * 1024) * 1024 + (size_t)h * 64;
  const size_t baseV = ((size_t)(bb * 16 + h) * 64) * 1024;
  const int qg = q0 + w * 16 + lr;
  const float* posrow = pos + ((size_t)h * 1024 + qg) * 1024;
  const u32* mrow = mbits + ((size_t)bb * 1024 + qg) * 32;

  // stage Q (128x64, swizzled via source permutation) + kt=0 K/V into buf0
#pragma unroll
  for (int i = 0; i < 2; ++i) {
    const int idx = i * 512 + t;
    const int r = idx >> 3;
    const int w8 = idx & 7;
    gload_lds16(Qm + baseQ + (size_t)(q0 + r) * 1024 + (w8 ^ (r & 7)) * 8, smem + idx * 16);
  }
  {
    const int r = t >> 3;
    const int w8 = t & 7;
    gload_lds16(Km + baseQ + (size_t)r * 1024 + (w8 ^ (r & 7)) * 8, smem + 16384 + t * 16);
    gload_lds16(Vt + baseV + (size_t)r * 1024 + (w8 ^ (r & 7)) * 8, smem + 24576 + t * 16);
  }

  // uniform-mask scan (1 bit per k; all-ones rows skip masking entirely)
  u32 ok = 0xffffffffu;
#pragma unroll
  for (int i = 0; i < 8; ++i) {
    const uint4 m4 = *(const uint4*)&mrow[i * 4];
    ok &= m4.x & m4.y & m4.z & m4.w;
  }
  const bool allone = __all(ok == 0xffffffffu);

  float4 pz[4];
#pragma unroll
  for (int n = 0; n < 4; ++n) pz[n] = *(const float4*)&posrow[n * 16 + lg * 4];

  __syncthreads();  // Q + buf0 landed

  // hoist Q fragments (B-operand)
  bfrag qv[2];
#pragma unroll
  for (int ks = 0; ks < 2; ++ks) {
    const int byt = (w * 16 + lr) * 128 + ((ks * 64 + lg * 16) ^ ((lr & 7) << 4));
    qv[ks] = *(const bfrag*)(smem + byt);
  }
  __syncthreads();  // everyone hoisted; sQ region may be overwritten

  f32x4 o[4] = {};
  float m_q = -3.0e38f, l_q = 0.f;

  for (int kt = 0; kt < 16; ++kt) {
    const int cur = kt & 1;
    const char* sK = smem + (cur ? 0 : 16384);
    const char* sV = smem + (cur ? 8192 : 24576);

    float4 pzn[4];
    if (kt < 15) {
      const int kn = (kt + 1) * 64;
      char* dK = smem + (cur ? 16384 : 0);
      char* dV = smem + (cur ? 24576 : 8192);
      const int r = t >> 3;
      const int w8 = t & 7;
      gload_lds16(Km + baseQ + (size_t)(kn + r) * 1024 + (w8 ^ (r & 7)) * 8, dK + t * 16);
      gload_lds16(Vt + baseV + (size_t)r * 1024 + kn + (w8 ^ (r & 7)) * 8, dV + t * 16);
#pragma unroll
      for (int n = 0; n < 4; ++n) pzn[n] = *(const float4*)&posrow[kn + n * 16 + lg * 4];
    }

    // S^T[k][q] = mfma(K, Q); lane: k-local = n*16 + lg*4 + j, q = qg
    f32x4 s[4] = {};
    __builtin_amdgcn_s_setprio(1);
#pragma unroll
    for (int ks = 0; ks < 2; ++ks) {
#pragma unroll
      for (int n = 0; n < 4; ++n) {
        const int byt = (n * 16 + lr) * 128 + ((ks * 64 + lg * 16) ^ ((lr & 7) << 4));
        const bfrag kf = *(const bfrag*)(sK + byt);
        s[n] = __builtin_amdgcn_mfma_f32_16x16x32_bf16(kf, qv[ks], s[n], 0, 0, 0);
      }
    }
    __builtin_amdgcn_s_setprio(0);

    // pos add: pv = s + pos*log2e (fp32 pos, FMA; exp2 domain)
    float pv[16];
#pragma unroll
    for (int n = 0; n < 4; ++n) {
      pv[n * 4 + 0] = fmaf(pz[n].x, log2e, s[n][0]);
      pv[n * 4 + 1] = fmaf(pz[n].y, log2e, s[n][1]);
      pv[n * 4 + 2] = fmaf(pz[n].z, log2e, s[n][2]);
      pv[n * 4 + 3] = fmaf(pz[n].w, log2e, s[n][3]);
    }

    if (!allone) {   // wave-uniform; never taken for all-ones masks
      const u32 a0 = mrow[kt * 2], a1 = mrow[kt * 2 + 1];
#pragma unroll
      for (int n = 0; n < 4; ++n)
#pragma unroll
        for (int j = 0; j < 4; ++j) {
          const int kl = n * 16 + lg * 4 + j;
          const u32 mw = (kl & 32) ? a1 : a0;
          if (!((mw >> (kl & 31)) & 1u)) pv[n * 4 + j] = -1.0e9f;
        }
    }

    // max over 16 (v_max3 tree) + cross-group
    float tmax = fmax3(pv[0], pv[1], pv[2]);
    tmax = fmax3(tmax, pv[3], pv[4]);
    tmax = fmax3(tmax, pv[5], pv[6]);
    tmax = fmax3(tmax, pv[7], pv[8]);
    tmax = fmax3(tmax, pv[9], pv[10]);
    tmax = fmax3(tmax, pv[11], pv[12]);
    tmax = fmax3(tmax, pv[13], pv[14]);
    tmax = fmaxf(tmax, pv[15]);
    tmax = fmaxf(tmax, __shfl_xor(tmax, 16));
    tmax = fmaxf(tmax, __shfl_xor(tmax, 32));

    if (!__all(tmax <= m_q + 8.0f)) {       // defer-max (T13)
      const float mn = fmaxf(m_q, tmax);
      const float sc = __builtin_amdgcn_exp2f(m_q - mn);
      l_q *= sc;
#pragma unroll
      for (int j = 0; j < 4; ++j) {
        const float scj = __shfl(sc, lg * 4 + j);
#pragma unroll
        for (int n = 0; n < 4; ++n) o[n][j] *= scj;
      }
      m_q = mn;
    }
    float rs = 0.f;
#pragma unroll
    for (int i2 = 0; i2 < 16; ++i2) {
      pv[i2] = __builtin_amdgcn_exp2f(pv[i2] - m_q);
      rs += pv[i2];
    }
    rs += __shfl_xor(rs, 16);
    rs += __shfl_xor(rs, 32);
    l_q += rs;

    // P -> per-wave swizzled LDS, read back as A-fragment
    char* pbuf = smem + 32768 + w * 2048;
#pragma unroll
    for (int n = 0; n < 4; ++n) {
      uint2 pk;
      pk.x = cvtpk(pv[n * 4 + 0], pv[n * 4 + 1]);
      pk.y = cvtpk(pv[n * 4 + 2], pv[n * 4 + 3]);
      const int byt = lr * 128 + ((n * 32 + lg * 8) ^ ((lr & 7) << 4));
      *(uint2*)(pbuf + byt) = pk;
    }
    __builtin_amdgcn_s_setprio(1);
#pragma unroll
    for (int ks = 0; ks < 2; ++ks) {
      const int pbyt = lr * 128 + ((ks * 64 + lg * 16) ^ ((lr & 7) << 4));
      const bfrag pf = *(const bfrag*)(pbuf + pbyt);
#pragma unroll
      for (int n = 0; n < 4; ++n) {
        const int vb = (n * 16 + lr) * 128 + ((ks * 64 + lg * 16) ^ ((lr & 7) << 4));
        const bfrag vf = *(const bfrag*)(sV + vb);
        o[n] = __builtin_amdgcn_mfma_f32_16x16x32_bf16(pf, vf, o[n], 0, 0, 0);
      }
    }
    __builtin_amdgcn_s_setprio(0);

    __syncthreads();   // drains prefetch vmcnt; next buffers ready

    if (kt < 15) {
#pragma unroll
      for (int n = 0; n < 4; ++n) pz[n] = pzn[n];
    }
  }

  // normalize + write x_attn[b, q, h*64 + d]
#pragma unroll
  for (int j = 0; j < 4; ++j) {
    const float lj = __shfl(l_q, lg * 4 + j);
    const float inv = 1.f / lj;
    const int qr = q0 + w * 16 + lg * 4 + j;
#pragma unroll
    for (int n = 0; n < 4; ++n)
      Om[baseQ + (size_t)qr * 1024 + n * 16 + lr] = f2bf_hw(o[n][j] * inv);
  }
}

// ---------------- launch ----------------

extern "C" void kernel_launch(void* const* d_in, const int* in_sizes, int n_in,
                              void* d_out, int out_size, void* d_ws, size_t ws_size,
                              hipStream_t stream) {
  const float* query = (const float*)d_in[0];
  const float* key_  = (const float*)d_in[1];
  const float* value = (const float*)d_in[2];
  const int*   mask  = (const int*)d_in[3];
  const float* pos   = (const float*)d_in[4];
  const float* wq = (const float*)d_in[5];
  const float* bq = (const float*)d_in[6];
  const float* wk = (const float*)d_in[7];
  const float* bk = (const float*)d_in[8];
  const float* wv = (const float*)d_in[9];
  const float* bv = (const float*)d_in[10];
  const float* wo = (const float*)d_in[11];
  const float* bo = (const float*)d_in[12];

  char* ws = (char*)d_ws;
  const size_t MB = 1024 * 1024;
  u16* wqb  = (u16*)(ws + 0 * MB);
  u16* wkb  = (u16*)(ws + 2 * MB);
  u16* wvb  = (u16*)(ws + 4 * MB);
  u16* wob  = (u16*)(ws + 6 * MB);
  u16* Qb   = (u16*)(ws + 40 * MB);    // 16MB
  u16* Kb   = (u16*)(ws + 56 * MB);
  u16* Vtb  = (u16*)(ws + 72 * MB);    // 16MB  [B,H,64,S] bf16 (V transposed)
  u16* Xa   = (u16*)(ws + 88 * MB);
  u32* mb   = (u32*)(ws + 104 * MB);   // 1MB bitmask
  u16* wotb = (u16*)(ws + 105 * MB);   // 2MB  Wo^T bf16
  u16* W2b  = (u16*)(ws + 107 * MB);   // 2MB  (Wo@Wo) bf16
  float* bo2 = (float*)(ws + 109 * MB);            // 4KB

  const float log2e = 1.4426950408889634f;
  const float qs = 0.0883883476483184f * log2e;   // (1/sqrt(2*dk)) * log2e

  // fused prep: weight casts + mask pack + Wo^T + bo2 in ONE launch
  prep_all<<<5632, 256, 0, stream>>>(wq, wk, wv, wo, wqb, wkb, wvb, wob,
                                     mask, mb, wotb, bo, bo2);

  // W2 = Wo @ Wo  (A = Wo bf16, W-input = Wo^T in [N][K] layout)
  gemm_bt_64<<<dim3(16, 16), 256, 0, stream>>>(wob, wotb, W2b, 1024, 1024);

  // fused Q/K/V projections: 3 x 512 blocks in ONE launch -> ~5 blocks/CU
  gemm_qkv<<<1536, 256, 0, stream>>>(query, key_, value, wqb, wkb, wvb,
                                     bq, bk, bv, Qb, Kb, Vtb, qs);

  attn_fwd<<<1024, 512, 0, stream>>>(Qb, Kb, Vtb, pos, mb, Xa);

  // out = Xa @ W2^T + bo2   (folds the doubled output linear)
  gemm_bt_a16<float><<<512, 256, 0, stream>>>(Xa, W2b, bo2, (float*)d_out, 8192, 1024, 1024);
}